// Round 1
// baseline (411.941 us; speedup 1.0000x reference)
//
#include <hip/hip_runtime.h>
#include <hip/hip_bf16.h>

// Problem constants (static in the reference): DIM=128 floats per row.
// batch = in_sizes[2], total_chunks = in_sizes[1], max_n_peaks = out_size/(batch*128).

#define SCAN_THREADS 256

// Kernel 1: single block.
//  - chunk_start[c] = exclusive prefix sum of chunk_size (global flat row offset)
//  - pool_start[i]  = exclusive prefix sum of (n_peaks[i]+1)
__global__ __launch_bounds__(SCAN_THREADS) void scan_kernel(
    const int* __restrict__ chunk_size, const int* __restrict__ n_peaks,
    int total_chunks, int batch,
    int* __restrict__ chunk_start, int* __restrict__ pool_start) {
  __shared__ int partials[SCAN_THREADS];
  const int t = threadIdx.x;
  const int items = (total_chunks + SCAN_THREADS - 1) / SCAN_THREADS;
  const int begin = t * items;
  const int end = min(begin + items, total_chunks);

  int local = 0;
  for (int i = begin; i < end; ++i) local += chunk_size[i];
  partials[t] = local;
  __syncthreads();

  // Hillis-Steele inclusive scan over the 256 partials
  for (int off = 1; off < SCAN_THREADS; off <<= 1) {
    int v = (t >= off) ? partials[t - off] : 0;
    __syncthreads();
    partials[t] += v;
    __syncthreads();
  }

  int run = (t == 0) ? 0 : partials[t - 1];
  for (int i = begin; i < end; ++i) {
    chunk_start[i] = run;
    run += chunk_size[i];
  }

  if (t == 0) {
    int acc = 0;
    for (int i = 0; i < batch; ++i) {
      pool_start[i] = acc;
      acc += n_peaks[i] + 1;
    }
  }
}

// Kernel 2: one block per (sample, peak slot). 256 threads.
// Thread t: dim4 = t&31 (32 float4 = 128 dims), row lane r0 = t>>5 (8 rows/iter).
__global__ __launch_bounds__(256) void pool_kernel(
    const float* __restrict__ x, const int* __restrict__ chunk_size,
    const int* __restrict__ n_peaks, const int* __restrict__ chunk_start,
    const int* __restrict__ pool_start, float* __restrict__ out,
    int max_n_peaks) {
  const int b = blockIdx.x;
  const int i = b / max_n_peaks;  // sample
  const int p = b % max_n_peaks;  // peak slot
  const int t = threadIdx.x;
  const int dim4 = t & 31;
  const int r0 = t >> 5;

  const int np = n_peaks[i];  // uniform within block
  float4 acc = make_float4(0.f, 0.f, 0.f, 0.f);
  int cnt = 1;

  if (p < np) {  // uniform branch
    const int c = pool_start[i] + p;
    const int start = chunk_start[c];
    const int size = chunk_size[c];
    cnt = size > 0 ? size : 1;
    const float4* __restrict__ xp = (const float4*)x + (size_t)start * 32;
    for (int r = r0; r < size; r += 8) {
      float4 v = xp[(size_t)r * 32 + dim4];
      acc.x += v.x; acc.y += v.y; acc.z += v.z; acc.w += v.w;
    }
  }

  __shared__ float4 red[256];
  red[t] = acc;
  __syncthreads();

  if (t < 32) {
    float4 s = red[t];
#pragma unroll
    for (int k = 1; k < 8; ++k) {
      float4 v = red[t + 32 * k];
      s.x += v.x; s.y += v.y; s.z += v.z; s.w += v.w;
    }
    const float inv = (p < np) ? (1.0f / (float)cnt) : 0.0f;
    float4 m = make_float4(s.x * inv, s.y * inv, s.z * inv, s.w * inv);
    ((float4*)out)[(size_t)b * 32 + t] = m;
  }
}

extern "C" void kernel_launch(void* const* d_in, const int* in_sizes, int n_in,
                              void* d_out, int out_size, void* d_ws, size_t ws_size,
                              hipStream_t stream) {
  const float* x = (const float*)d_in[0];
  const int* chunk_size = (const int*)d_in[1];
  const int* n_peaks = (const int*)d_in[2];
  const int total_chunks = in_sizes[1];
  const int batch = in_sizes[2];
  const int dim = 128;                              // static per reference
  const int max_n_peaks = out_size / (batch * dim); // 512
  float* out = (float*)d_out;

  int* chunk_start = (int*)d_ws;                 // total_chunks ints
  int* pool_start = chunk_start + total_chunks;  // batch ints

  scan_kernel<<<1, SCAN_THREADS, 0, stream>>>(chunk_size, n_peaks, total_chunks,
                                              batch, chunk_start, pool_start);

  const int grid = batch * max_n_peaks;  // 4096; every output row owned by one block
  pool_kernel<<<grid, 256, 0, stream>>>(x, chunk_size, n_peaks, chunk_start,
                                        pool_start, out, max_n_peaks);
}

// Round 2
// 369.719 us; speedup vs baseline: 1.1142x; 1.1142x over previous
//
#include <hip/hip_runtime.h>
#include <hip/hip_bf16.h>

// SplitPool: x (B=8, L=65536, D=128) fp32; per-chunk mean over contiguous row
// runs; scatter to (B, max_n_peaks=512, 128) with zero padding.
// Structure: scan (chunk offsets) -> split-sum (4 sub-blocks per chunk, no
// atomics) -> combine/scatter (sum 4 partials, scale, zero-pad).

#define SCAN_THREADS 256
#define NSPLIT 4

// Kernel 1: single block.
//  - chunk_start[c] = exclusive prefix sum of chunk_size (global flat row offset)
//  - pool_start[i]  = exclusive prefix sum of (n_peaks[i]+1)
__global__ __launch_bounds__(SCAN_THREADS) void scan_kernel(
    const int* __restrict__ chunk_size, const int* __restrict__ n_peaks,
    int total_chunks, int batch,
    int* __restrict__ chunk_start, int* __restrict__ pool_start) {
  __shared__ int partials[SCAN_THREADS];
  const int t = threadIdx.x;
  const int items = (total_chunks + SCAN_THREADS - 1) / SCAN_THREADS;
  const int begin = t * items;
  const int end = min(begin + items, total_chunks);

  int local = 0;
  for (int i = begin; i < end; ++i) local += chunk_size[i];
  partials[t] = local;
  __syncthreads();

  for (int off = 1; off < SCAN_THREADS; off <<= 1) {
    int v = (t >= off) ? partials[t - off] : 0;
    __syncthreads();
    partials[t] += v;
    __syncthreads();
  }

  int run = (t == 0) ? 0 : partials[t - 1];
  for (int i = begin; i < end; ++i) {
    chunk_start[i] = run;
    run += chunk_size[i];
  }

  if (t == 0) {
    int acc = 0;
    for (int i = 0; i < batch; ++i) {
      pool_start[i] = acc;
      acc += n_peaks[i] + 1;
    }
  }
}

// Kernel 2: one block per (chunk, split). 256 threads = 8 row-lanes x 32 dim4.
// Each block sums its quarter of the chunk's rows and writes a partial
// (128 floats) to split_sums[(c*NSPLIT+s)*128 ..]. No atomics, no init needed.
__global__ __launch_bounds__(256) void split_sum_kernel(
    const float* __restrict__ x, const int* __restrict__ chunk_size,
    const int* __restrict__ chunk_start, float4* __restrict__ split_sums) {
  const int c = blockIdx.x >> 2;   // chunk
  const int s = blockIdx.x & 3;    // split
  const int t = threadIdx.x;
  const int dim4 = t & 31;
  const int r0 = t >> 5;

  const int start = chunk_start[c];
  const int size = chunk_size[c];
  const int rps = (size + NSPLIT - 1) >> 2;  // rows per split
  const int r_begin = s * rps;
  const int r_end = min(r_begin + rps, size);

  const float4* __restrict__ xp = (const float4*)x + (size_t)start * 32;
  float4 acc = make_float4(0.f, 0.f, 0.f, 0.f);
#pragma unroll 4
  for (int r = r_begin + r0; r < r_end; r += 8) {
    float4 v = xp[(size_t)r * 32 + dim4];
    acc.x += v.x; acc.y += v.y; acc.z += v.z; acc.w += v.w;
  }

  __shared__ float4 red[256];
  red[t] = acc;
  __syncthreads();

  if (t < 32) {
    float4 sum = red[t];
#pragma unroll
    for (int k = 1; k < 8; ++k) {
      float4 v = red[t + 32 * k];
      sum.x += v.x; sum.y += v.y; sum.z += v.z; sum.w += v.w;
    }
    split_sums[((size_t)blockIdx.x) * 32 + t] = sum;
  }
}

// Kernel 3: combine + scale + scatter. 256 threads per block = 8 output slots.
// slot = (sample i, peak p). Valid -> sum 4 partials / count; else 0.
__global__ __launch_bounds__(256) void combine_kernel(
    const float4* __restrict__ split_sums, const int* __restrict__ chunk_size,
    const int* __restrict__ n_peaks, const int* __restrict__ pool_start,
    float4* __restrict__ out, int max_n_peaks, int n_slots) {
  const int t = threadIdx.x;
  const int slot = blockIdx.x * 8 + (t >> 5);
  const int dim4 = t & 31;
  if (slot >= n_slots) return;
  const int i = slot / max_n_peaks;
  const int p = slot % max_n_peaks;

  float4 m = make_float4(0.f, 0.f, 0.f, 0.f);
  if (p < n_peaks[i]) {
    const int c = pool_start[i] + p;
    float4 sum = make_float4(0.f, 0.f, 0.f, 0.f);
#pragma unroll
    for (int k = 0; k < NSPLIT; ++k) {
      float4 v = split_sums[((size_t)c * NSPLIT + k) * 32 + dim4];
      sum.x += v.x; sum.y += v.y; sum.z += v.z; sum.w += v.w;
    }
    const int sz = chunk_size[c];
    const float inv = 1.0f / (float)(sz > 0 ? sz : 1);
    m = make_float4(sum.x * inv, sum.y * inv, sum.z * inv, sum.w * inv);
  }
  out[(size_t)slot * 32 + dim4] = m;
}

extern "C" void kernel_launch(void* const* d_in, const int* in_sizes, int n_in,
                              void* d_out, int out_size, void* d_ws, size_t ws_size,
                              hipStream_t stream) {
  const float* x = (const float*)d_in[0];
  const int* chunk_size = (const int*)d_in[1];
  const int* n_peaks = (const int*)d_in[2];
  const int total_chunks = in_sizes[1];
  const int batch = in_sizes[2];
  const int dim = 128;                              // static per reference
  const int max_n_peaks = out_size / (batch * dim); // 512
  float* out = (float*)d_out;

  // Workspace layout: [chunk_start: total_chunks ints][pool_start: batch ints]
  // [pad to 16B][split_sums: total_chunks*NSPLIT*128 floats]
  int* chunk_start = (int*)d_ws;
  int* pool_start = chunk_start + total_chunks;
  size_t off = ((size_t)(total_chunks + batch) * sizeof(int) + 15) & ~(size_t)15;
  float4* split_sums = (float4*)((char*)d_ws + off);

  scan_kernel<<<1, SCAN_THREADS, 0, stream>>>(chunk_size, n_peaks, total_chunks,
                                              batch, chunk_start, pool_start);

  split_sum_kernel<<<total_chunks * NSPLIT, 256, 0, stream>>>(
      x, chunk_size, chunk_start, split_sums);

  const int n_slots = batch * max_n_peaks;  // 4096
  combine_kernel<<<(n_slots + 7) / 8, 256, 0, stream>>>(
      split_sums, chunk_size, n_peaks, pool_start, (float4*)out, max_n_peaks,
      n_slots);
}